// Round 3
// baseline (530.571 us; speedup 1.0000x reference)
//
#include <hip/hip_runtime.h>
#include <hip/hip_bf16.h>
#include <stdint.h>

#define AS_GLOBAL __attribute__((address_space(1)))
#define AS_LDS    __attribute__((address_space(3)))

typedef __attribute__((ext_vector_type(8))) short  bf16x8;
typedef __attribute__((ext_vector_type(4))) float  f32x4;
typedef __attribute__((ext_vector_type(4))) short  s16x4;

__device__ __forceinline__ void gload_lds16(const void* g, void* l) {
    __builtin_amdgcn_global_load_lds((AS_GLOBAL const void*)g, (AS_LDS void*)l, 16, 0, 0);
}

// fp32 -> bf16 for x, W1, W2, W3 (exact-cover grid, no tail).
__global__ void cast_all_k(const float* __restrict__ x,  const float* __restrict__ W1,
                           const float* __restrict__ W2, const float* __restrict__ W3,
                           __hip_bfloat16* __restrict__ xb,  __hip_bfloat16* __restrict__ W1b,
                           __hip_bfloat16* __restrict__ W2b, __hip_bfloat16* __restrict__ W3b) {
    const long n0 = 2097152 / 4, n1 = 8388608 / 4, n2 = 16777216 / 4;
    long i4 = (long)blockIdx.x * 256 + threadIdx.x;   // float4 index
    const float* s; __hip_bfloat16* d; long off;
    if      (i4 < n0)           { s = x;  d = xb;  off = i4; }
    else if (i4 < n0 + n1)      { s = W1; d = W1b; off = i4 - n0; }
    else if (i4 < n0 + n1 + n2) { s = W2; d = W2b; off = i4 - n0 - n1; }
    else                        { s = W3; d = W3b; off = i4 - n0 - n1 - n2; }
    float4 v = ((const float4*)s)[off];
    union { s16x4 p; __hip_bfloat16 h[4]; } u;
    u.h[0] = __float2bfloat16(v.x);
    u.h[1] = __float2bfloat16(v.y);
    u.h[2] = __float2bfloat16(v.z);
    u.h[3] = __float2bfloat16(v.w);
    ((s16x4*)d)[off] = u.p;
}

// Split-K GEMM with fused "last block reduces" epilogue.
// P[z][M,N] = A[M,k0:k1] @ B[N,k0:k1]^T (fp32 partials). Tile counter in cnt;
// the last-arriving block per (bm,bn) sums all S partials and applies epilogue:
// MODE 0: bf16 out = relu(sum + bias)          MODE 1: bf16 out = T-collapse
// MODE 2: f32  out = sum + (1-beta3^T)*bias
// BK=64, XOR-swizzled LDS: row r stores global granule g (16B) at slot g^(r&7).
template <int MODE>
__global__ __launch_bounds__(256, 2)
void gemm_fused(const __hip_bfloat16* __restrict__ A,
                const __hip_bfloat16* __restrict__ Bm,
                float* __restrict__ P,
                int* __restrict__ cnt,
                void* __restrict__ outv,
                const int M, const int N, const int kchunk,
                const float* __restrict__ bias,
                const float* __restrict__ b_taus,
                const int* __restrict__ Tp)
{
    __shared__ __hip_bfloat16 As[128 * 64];
    __shared__ __hip_bfloat16 Bs[128 * 64];
    __shared__ int sh_old;

    const int tid  = threadIdx.x;
    const int lane = tid & 63;
    const int wave = tid >> 6;
    const int wm   = wave >> 1, wn = wave & 1;
    const int lm   = lane & 15, lq = lane >> 4;

    const int bn = blockIdx.x, bm = blockIdx.y, kz = blockIdx.z;
    const int S  = gridDim.z;
    const int K  = kchunk * S;
    const int k0 = kz * kchunk;

    const int rlo  = lane >> 3;                  // row within an 8-row staging chunk
    const int gsw8 = (((lane & 7) ^ rlo) << 3);  // swizzled granule -> element offset

    const __hip_bfloat16* Ag = A  + (size_t)(bm * 128) * K;
    const __hip_bfloat16* Bg = Bm + (size_t)(bn * 128) * K;

    f32x4 acc[4][4];
    #pragma unroll
    for (int i = 0; i < 4; ++i)
        #pragma unroll
        for (int j = 0; j < 4; ++j)
            acc[i][j] = (f32x4){0.f, 0.f, 0.f, 0.f};

    for (int kt = k0; kt < k0 + kchunk; kt += 64) {
        __syncthreads();
        #pragma unroll
        for (int c = 0; c < 4; ++c) {
            const int chunk = wave * 4 + c;      // 0..15, wave-uniform
            const int row   = chunk * 8 + rlo;   // local tile row 0..127
            gload_lds16(Ag + (size_t)row * K + kt + gsw8, As + chunk * 512);
            gload_lds16(Bg + (size_t)row * K + kt + gsw8, Bs + chunk * 512);
        }
        __syncthreads();
        #pragma unroll
        for (int kk = 0; kk < 2; ++kk) {
            // need granule G = kk*4+lq of row; it lives at slot G^(row&7), row&7 == lm&7
            const int sl = (((kk * 4 + lq) ^ (lm & 7)) << 3);
            bf16x8 af[4], bf[4];
            #pragma unroll
            for (int i = 0; i < 4; ++i)
                af[i] = *(const bf16x8*)(As + (wm * 64 + i * 16 + lm) * 64 + sl);
            #pragma unroll
            for (int j = 0; j < 4; ++j)
                bf[j] = *(const bf16x8*)(Bs + (wn * 64 + j * 16 + lm) * 64 + sl);
            #pragma unroll
            for (int i = 0; i < 4; ++i)
                #pragma unroll
                for (int j = 0; j < 4; ++j)
                    acc[i][j] = __builtin_amdgcn_mfma_f32_16x16x32_bf16(af[i], bf[j], acc[i][j], 0, 0, 0);
        }
    }

    const size_t MN   = (size_t)M * N;
    const int    row0 = bm * 128 + wm * 64;
    const int    colb = bn * 128 + wn * 64 + lm;

    // 1. write own partial
    float* Pz = P + (size_t)kz * MN;
    #pragma unroll
    for (int j = 0; j < 4; ++j) {
        const int col = colb + j * 16;
        #pragma unroll
        for (int i = 0; i < 4; ++i)
            #pragma unroll
            for (int r = 0; r < 4; ++r)
                Pz[(size_t)(row0 + i * 16 + lq * 4 + r) * N + col] = acc[i][j][r];
    }

    // 2. release-signal; last arriving block reduces
    __syncthreads();   // drains vmcnt(0): all partial stores out of the CU
    if (tid == 0)
        sh_old = __hip_atomic_fetch_add(&cnt[bm * gridDim.x + bn], 1,
                                        __ATOMIC_RELEASE, __HIP_MEMORY_SCOPE_AGENT);
    __syncthreads();
    if (sh_old != S - 1) return;

    if (tid == 0) __threadfence();   // acquire: invalidate L1/L2 so partial reads are fresh
    __syncthreads();

    // 3. sum all S partials (skip own, it's still in acc)
    #pragma unroll
    for (int j = 0; j < 4; ++j) {
        const int col = colb + j * 16;
        #pragma unroll
        for (int i = 0; i < 4; ++i)
            #pragma unroll
            for (int r = 0; r < 4; ++r) {
                const size_t idx = (size_t)(row0 + i * 16 + lq * 4 + r) * N + col;
                float v = acc[i][j][r];
                for (int s = 0; s < S; ++s)
                    if (s != kz) v += P[s * MN + idx];
                acc[i][j][r] = v;
            }
    }

    // 4. epilogue
    if constexpr (MODE == 0) {
        __hip_bfloat16* C = (__hip_bfloat16*)outv;
        #pragma unroll
        for (int j = 0; j < 4; ++j) {
            const int col = colb + j * 16;
            const float bv = bias[col];
            #pragma unroll
            for (int i = 0; i < 4; ++i)
                #pragma unroll
                for (int r = 0; r < 4; ++r) {
                    const int row = row0 + i * 16 + lq * 4 + r;
                    C[(size_t)row * N + col] = __float2bfloat16(fmaxf(acc[i][j][r] + bv, 0.f));
                }
        }
    } else if constexpr (MODE == 1) {
        const int   T   = *Tp;
        const float be1 = 1.f / (1.f + expf(-b_taus[0]));
        const float be2 = 1.f / (1.f + expf(-b_taus[1]));
        const float be3 = 1.f / (1.f + expf(-b_taus[2]));
        __hip_bfloat16* C = (__hip_bfloat16*)outv;
        #pragma unroll
        for (int j = 0; j < 4; ++j) {
            const int col = colb + j * 16;
            const float bv = bias[col];
            #pragma unroll
            for (int i = 0; i < 4; ++i)
                #pragma unroll
                for (int r = 0; r < 4; ++r) {
                    const int row = row0 + i * 16 + lq * 4 + r;
                    const float y = acc[i][j][r];
                    float p1 = 1.f, s2 = 0.f, za = 0.f;
                    for (int t = 0; t < T; ++t) {
                        p1 *= be1;
                        const float d2 = fmaxf(fmaf(1.f - p1, y, bv), 0.f);
                        s2 = be2 * s2 + (1.f - be2) * d2;
                        za = be3 * za + (1.f - be3) * s2;
                    }
                    C[(size_t)row * N + col] = __float2bfloat16(za);
                }
        }
    } else {
        const int   T   = *Tp;
        const float be3 = 1.f / (1.f + expf(-b_taus[2]));
        float g = 0.f;
        for (int t = 0; t < T; ++t) g = be3 * g + (1.f - be3);   // 1 - beta3^T
        float* C = (float*)outv;
        #pragma unroll
        for (int j = 0; j < 4; ++j) {
            const int col = colb + j * 16;
            const float bv = g * bias[col];
            #pragma unroll
            for (int i = 0; i < 4; ++i)
                #pragma unroll
                for (int r = 0; r < 4; ++r) {
                    const int row = row0 + i * 16 + lq * 4 + r;
                    C[(size_t)row * N + col] = acc[i][j][r] + bv;
                }
        }
    }
}

extern "C" void kernel_launch(void* const* d_in, const int* in_sizes, int n_in,
                              void* d_out, int out_size, void* d_ws, size_t ws_size,
                              hipStream_t stream) {
    const float* x      = (const float*)d_in[0];
    const float* W1     = (const float*)d_in[1];
    const float* b1     = (const float*)d_in[2];
    const float* W2     = (const float*)d_in[3];
    const float* b2     = (const float*)d_in[4];
    const float* W3     = (const float*)d_in[5];
    const float* b3     = (const float*)d_in[6];
    const float* b_taus = (const float*)d_in[7];
    const int*   Tp     = (const int*)d_in[8];

    const int B = 1024, DIN = 2048, H1 = 4096, H2 = 4096, DOUT = 1024;
    const long MB = 1024 * 1024;

    // Arena (120 MB + 3 KB counters), phase-aliased:
    //  phase1: xb 0..4, W1b 4..20, P1 20..52
    //  phase2: P2 0..64          phase3: P3 0..32
    //  static: W2b 64..96, W3b 96..104, D1b 104..112, Sb 112..120, cnt @120
    char* ws = (char*)d_ws;
    __hip_bfloat16* xb  = (__hip_bfloat16*)(ws + 0);
    __hip_bfloat16* W1b = (__hip_bfloat16*)(ws + 4 * MB);
    float*          P1  = (float*)         (ws + 20 * MB);
    float*          P2  = (float*)         (ws + 0);
    float*          P3  = (float*)         (ws + 0);
    __hip_bfloat16* W2b = (__hip_bfloat16*)(ws + 64 * MB);
    __hip_bfloat16* W3b = (__hip_bfloat16*)(ws + 96 * MB);
    __hip_bfloat16* D1b = (__hip_bfloat16*)(ws + 104 * MB);
    __hip_bfloat16* Sb  = (__hip_bfloat16*)(ws + 112 * MB);
    int*            cnt1 = (int*)(ws + 120 * MB);        // 256 tiles
    int*            cnt2 = cnt1 + 256;                   // 256 tiles
    int*            cnt3 = cnt2 + 256;                   // 64 tiles

    hipMemsetAsync(cnt1, 0, (256 + 256 + 64) * sizeof(int), stream);

    // casts: 7,864,320 float4s exactly
    cast_all_k<<<dim3(30720), dim3(256), 0, stream>>>(x, W1, W2, W3, xb, W1b, W2b, W3b);

    // Layer 1: D1 = relu(x @ W1^T + b1), split-K S=2
    gemm_fused<0><<<dim3(H1 / 128, B / 128, 2), 256, 0, stream>>>(
        xb, W1b, P1, cnt1, (void*)D1b, B, H1, DIN / 2, b1, nullptr, nullptr);
    // Layer 2 + T-collapse: Z, split-K S=4
    gemm_fused<1><<<dim3(H2 / 128, B / 128, 4), 256, 0, stream>>>(
        D1b, W2b, P2, cnt2, (void*)Sb, B, H2, H1 / 4, b2, b_taus, Tp);
    // Layer 3: out = Z @ W3^T + (1-beta3^T)*b3, split-K S=8, fp32 out
    gemm_fused<2><<<dim3(DOUT / 128, B / 128, 8), 256, 0, stream>>>(
        Sb, W3b, P3, cnt3, d_out, B, DOUT, H2 / 8, b3, b_taus, Tp);
}

// Round 4
// 269.959 us; speedup vs baseline: 1.9654x; 1.9654x over previous
//
#include <hip/hip_runtime.h>
#include <hip/hip_bf16.h>
#include <stdint.h>

#define AS_GLOBAL __attribute__((address_space(1)))
#define AS_LDS    __attribute__((address_space(3)))

typedef __attribute__((ext_vector_type(8))) short  bf16x8;
typedef __attribute__((ext_vector_type(4))) float  f32x4;
typedef __attribute__((ext_vector_type(4))) short  s16x4;

__device__ __forceinline__ void gload_lds16(const void* g, void* l) {
    __builtin_amdgcn_global_load_lds((AS_GLOBAL const void*)g, (AS_LDS void*)l, 16, 0, 0);
}

// fp32 -> bf16 for x, W1, W2, W3 (exact-cover grid, no tail).
__global__ void cast_all_k(const float* __restrict__ x,  const float* __restrict__ W1,
                           const float* __restrict__ W2, const float* __restrict__ W3,
                           __hip_bfloat16* __restrict__ xb,  __hip_bfloat16* __restrict__ W1b,
                           __hip_bfloat16* __restrict__ W2b, __hip_bfloat16* __restrict__ W3b) {
    const long n0 = 2097152 / 4, n1 = 8388608 / 4, n2 = 16777216 / 4;
    long i4 = (long)blockIdx.x * 256 + threadIdx.x;   // float4 index
    const float* s; __hip_bfloat16* d; long off;
    if      (i4 < n0)           { s = x;  d = xb;  off = i4; }
    else if (i4 < n0 + n1)      { s = W1; d = W1b; off = i4 - n0; }
    else if (i4 < n0 + n1 + n2) { s = W2; d = W2b; off = i4 - n0 - n1; }
    else                        { s = W3; d = W3b; off = i4 - n0 - n1 - n2; }
    float4 v = ((const float4*)s)[off];
    union { s16x4 p; __hip_bfloat16 h[4]; } u;
    u.h[0] = __float2bfloat16(v.x);
    u.h[1] = __float2bfloat16(v.y);
    u.h[2] = __float2bfloat16(v.z);
    u.h[3] = __float2bfloat16(v.w);
    ((s16x4*)d)[off] = u.p;
}

// Split-K GEMM: P[z][M,N] = A[M,k0:k1] @ B[N,k0:k1]^T (fp32 partials, no epilogue).
// grid = (N/128, M/128, S). 128x128 tile, BK=64, 4 waves of 4x4 16x16x32 MFMA.
// XOR-swizzled LDS (conflict-free, verified R3): row r stores 16B granule g at slot g^(r&7).
__global__ __launch_bounds__(256, 2)
void gemm_btk(const __hip_bfloat16* __restrict__ A,
              const __hip_bfloat16* __restrict__ Bm,
              float* __restrict__ P,
              const int M, const int N, const int kchunk)
{
    __shared__ __hip_bfloat16 As[128 * 64];
    __shared__ __hip_bfloat16 Bs[128 * 64];

    const int tid  = threadIdx.x;
    const int lane = tid & 63;
    const int wave = tid >> 6;
    const int wm   = wave >> 1, wn = wave & 1;
    const int lm   = lane & 15, lq = lane >> 4;

    const int bn = blockIdx.x, bm = blockIdx.y, kz = blockIdx.z;
    const int K  = kchunk * gridDim.z;
    const int k0 = kz * kchunk;

    const int rlo  = lane >> 3;                  // row within an 8-row staging chunk
    const int gsw8 = (((lane & 7) ^ rlo) << 3);  // swizzled granule -> element offset

    const __hip_bfloat16* Ag = A  + (size_t)(bm * 128) * K;
    const __hip_bfloat16* Bg = Bm + (size_t)(bn * 128) * K;

    f32x4 acc[4][4];
    #pragma unroll
    for (int i = 0; i < 4; ++i)
        #pragma unroll
        for (int j = 0; j < 4; ++j)
            acc[i][j] = (f32x4){0.f, 0.f, 0.f, 0.f};

    for (int kt = k0; kt < k0 + kchunk; kt += 64) {
        __syncthreads();
        #pragma unroll
        for (int c = 0; c < 4; ++c) {
            const int chunk = wave * 4 + c;      // 0..15, wave-uniform
            const int row   = chunk * 8 + rlo;   // local tile row 0..127
            gload_lds16(Ag + (size_t)row * K + kt + gsw8, As + chunk * 512);
            gload_lds16(Bg + (size_t)row * K + kt + gsw8, Bs + chunk * 512);
        }
        __syncthreads();
        #pragma unroll
        for (int kk = 0; kk < 2; ++kk) {
            // granule G = kk*4+lq of row lives at slot G^(row&7); row&7 == lm&7
            const int sl = (((kk * 4 + lq) ^ (lm & 7)) << 3);
            bf16x8 af[4], bf[4];
            #pragma unroll
            for (int i = 0; i < 4; ++i)
                af[i] = *(const bf16x8*)(As + (wm * 64 + i * 16 + lm) * 64 + sl);
            #pragma unroll
            for (int j = 0; j < 4; ++j)
                bf[j] = *(const bf16x8*)(Bs + (wn * 64 + j * 16 + lm) * 64 + sl);
            #pragma unroll
            for (int i = 0; i < 4; ++i)
                #pragma unroll
                for (int j = 0; j < 4; ++j)
                    acc[i][j] = __builtin_amdgcn_mfma_f32_16x16x32_bf16(af[i], bf[j], acc[i][j], 0, 0, 0);
        }
    }

    float* Pz = P + (size_t)kz * M * N;
    const int row0 = bm * 128 + wm * 64;
    const int colb = bn * 128 + wn * 64 + lm;
    #pragma unroll
    for (int j = 0; j < 4; ++j) {
        const int col = colb + j * 16;
        #pragma unroll
        for (int i = 0; i < 4; ++i)
            #pragma unroll
            for (int r = 0; r < 4; ++r) {
                const int row = row0 + i * 16 + lq * 4 + r;
                Pz[(size_t)row * N + col] = acc[i][j][r];
            }
    }
}

// Sum S split-K partials + epilogue (dense, float4, memory-bound).
// MODE 0: bf16 out = relu(sum + bias)            (layer1 -> D1)
// MODE 1: bf16 out = T-collapse(y=sum, b2)       (layer2 -> Z)
// MODE 2: f32  out = sum + (1-beta3^T)*bias      (layer3 -> s3_T)
template <int MODE>
__global__ void reduce_k(const float* __restrict__ P, const int S,
                         void* __restrict__ outv, const long MN, const int N,
                         const float* __restrict__ bias,
                         const float* __restrict__ b_taus,
                         const int* __restrict__ Tp)
{
    long i4 = (long)blockIdx.x * 256 + threadIdx.x;   // float4 index, exact cover
    long i  = i4 * 4;
    float4 a = ((const float4*)P)[i4];
    for (int s = 1; s < S; ++s) {
        float4 b = ((const float4*)(P + (size_t)s * MN))[i4];
        a.x += b.x; a.y += b.y; a.z += b.z; a.w += b.w;
    }
    const int col = (int)(i % N);
    const float4 bv = *(const float4*)(bias + col);

    if constexpr (MODE == 0) {
        union { s16x4 p; __hip_bfloat16 h[4]; } u;
        u.h[0] = __float2bfloat16(fmaxf(a.x + bv.x, 0.f));
        u.h[1] = __float2bfloat16(fmaxf(a.y + bv.y, 0.f));
        u.h[2] = __float2bfloat16(fmaxf(a.z + bv.z, 0.f));
        u.h[3] = __float2bfloat16(fmaxf(a.w + bv.w, 0.f));
        ((s16x4*)outv)[i4] = u.p;
    } else if constexpr (MODE == 1) {
        const int   T   = *Tp;
        const float be1 = 1.f / (1.f + expf(-b_taus[0]));
        const float be2 = 1.f / (1.f + expf(-b_taus[1]));
        const float be3 = 1.f / (1.f + expf(-b_taus[2]));
        float y[4] = {a.x, a.y, a.z, a.w};
        float bb[4] = {bv.x, bv.y, bv.z, bv.w};
        union { s16x4 p; __hip_bfloat16 h[4]; } u;
        #pragma unroll
        for (int c = 0; c < 4; ++c) {
            float p1 = 1.f, s2 = 0.f, za = 0.f;
            for (int t = 0; t < T; ++t) {
                p1 *= be1;
                const float d2 = fmaxf(fmaf(1.f - p1, y[c], bb[c]), 0.f);
                s2 = be2 * s2 + (1.f - be2) * d2;
                za = be3 * za + (1.f - be3) * s2;
            }
            u.h[c] = __float2bfloat16(za);
        }
        ((s16x4*)outv)[i4] = u.p;
    } else {
        const int   T   = *Tp;
        const float be3 = 1.f / (1.f + expf(-b_taus[2]));
        float g = 0.f;
        for (int t = 0; t < T; ++t) g = be3 * g + (1.f - be3);   // 1 - beta3^T
        float4 o;
        o.x = a.x + g * bv.x;
        o.y = a.y + g * bv.y;
        o.z = a.z + g * bv.z;
        o.w = a.w + g * bv.w;
        ((float4*)outv)[i4] = o;
    }
}

extern "C" void kernel_launch(void* const* d_in, const int* in_sizes, int n_in,
                              void* d_out, int out_size, void* d_ws, size_t ws_size,
                              hipStream_t stream) {
    const float* x      = (const float*)d_in[0];
    const float* W1     = (const float*)d_in[1];
    const float* b1     = (const float*)d_in[2];
    const float* W2     = (const float*)d_in[3];
    const float* b2     = (const float*)d_in[4];
    const float* W3     = (const float*)d_in[5];
    const float* b3     = (const float*)d_in[6];
    const float* b_taus = (const float*)d_in[7];
    const int*   Tp     = (const int*)d_in[8];

    const int B = 1024, DIN = 2048, H1 = 4096, H2 = 4096, DOUT = 1024;
    const long MB = 1024 * 1024;

    // Arena (120 MB), phase-aliased:
    //  phase1: xb 0..4, W1b 4..20, P1 20..52
    //  phase2: P2 0..64          phase3: P3 0..32
    //  static: W2b 64..96, W3b 96..104, D1b 104..112, Sb 112..120
    char* ws = (char*)d_ws;
    __hip_bfloat16* xb  = (__hip_bfloat16*)(ws + 0);
    __hip_bfloat16* W1b = (__hip_bfloat16*)(ws + 4 * MB);
    float*          P1  = (float*)         (ws + 20 * MB);
    float*          P2  = (float*)         (ws + 0);
    float*          P3  = (float*)         (ws + 0);
    __hip_bfloat16* W2b = (__hip_bfloat16*)(ws + 64 * MB);
    __hip_bfloat16* W3b = (__hip_bfloat16*)(ws + 96 * MB);
    __hip_bfloat16* D1b = (__hip_bfloat16*)(ws + 104 * MB);
    __hip_bfloat16* Sb  = (__hip_bfloat16*)(ws + 112 * MB);

    // casts: 7,864,320 float4s exactly
    cast_all_k<<<dim3(30720), dim3(256), 0, stream>>>(x, W1, W2, W3, xb, W1b, W2b, W3b);

    // Layer 1: P1 = split-K(x @ W1^T), S=2   (512 blocks)
    gemm_btk<<<dim3(H1 / 128, B / 128, 2), 256, 0, stream>>>(xb, W1b, P1, B, H1, DIN / 2);
    reduce_k<0><<<dim3(4096), 256, 0, stream>>>(P1, 2, (void*)D1b, (long)B * H1, H1, b1, nullptr, nullptr);

    // Layer 2: P2 = split-K(D1 @ W2^T), S=4  (1024 blocks)
    gemm_btk<<<dim3(H2 / 128, B / 128, 4), 256, 0, stream>>>(D1b, W2b, P2, B, H2, H1 / 4);
    reduce_k<1><<<dim3(4096), 256, 0, stream>>>(P2, 4, (void*)Sb, (long)B * H2, H2, b2, b_taus, Tp);

    // Layer 3: P3 = split-K(Z @ W3^T), S=8   (512 blocks)
    gemm_btk<<<dim3(DOUT / 128, B / 128, 8), 256, 0, stream>>>(Sb, W3b, P3, B, DOUT, H2 / 8);
    reduce_k<2><<<dim3(1024), 256, 0, stream>>>(P3, 8, d_out, (long)B * DOUT, DOUT, b3, b_taus, Tp);
}

// Round 5
// 265.374 us; speedup vs baseline: 1.9993x; 1.0173x over previous
//
#include <hip/hip_runtime.h>
#include <hip/hip_bf16.h>
#include <stdint.h>

#define AS_GLOBAL __attribute__((address_space(1)))
#define AS_LDS    __attribute__((address_space(3)))

typedef __attribute__((ext_vector_type(8))) short  bf16x8;
typedef __attribute__((ext_vector_type(4))) float  f32x4;
typedef __attribute__((ext_vector_type(4))) short  s16x4;
typedef __attribute__((ext_vector_type(8))) short  s16x8;

__device__ __forceinline__ void gload_lds16(const void* g, void* l) {
    __builtin_amdgcn_global_load_lds((AS_GLOBAL const void*)g, (AS_LDS void*)l, 16, 0, 0);
}

// fp32 -> bf16 for x, W1, W2, W3. 8 floats/thread: 2x float4 NT loads, 1x 16B store.
// Exact cover: 3,932,160 pairs = 15360 blocks x 256. All region bounds even in float4.
__global__ void cast_all_k(const float* __restrict__ x,  const float* __restrict__ W1,
                           const float* __restrict__ W2, const float* __restrict__ W3,
                           __hip_bfloat16* __restrict__ xb,  __hip_bfloat16* __restrict__ W1b,
                           __hip_bfloat16* __restrict__ W2b, __hip_bfloat16* __restrict__ W3b) {
    const long n0 = 2097152 / 4, n1 = 8388608 / 4, n2 = 16777216 / 4;
    long p  = (long)blockIdx.x * 256 + threadIdx.x;   // pair-of-float4 index
    long i4 = p * 2;
    const float* s; __hip_bfloat16* d; long off;
    if      (i4 < n0)           { s = x;  d = xb;  off = i4; }
    else if (i4 < n0 + n1)      { s = W1; d = W1b; off = i4 - n0; }
    else if (i4 < n0 + n1 + n2) { s = W2; d = W2b; off = i4 - n0 - n1; }
    else                        { s = W3; d = W3b; off = i4 - n0 - n1 - n2; }
    f32x4 a = __builtin_nontemporal_load(((const f32x4*)s) + off);
    f32x4 b = __builtin_nontemporal_load(((const f32x4*)s) + off + 1);
    union { s16x8 p8; __hip_bfloat16 h[8]; } u;
    u.h[0] = __float2bfloat16(a.x); u.h[1] = __float2bfloat16(a.y);
    u.h[2] = __float2bfloat16(a.z); u.h[3] = __float2bfloat16(a.w);
    u.h[4] = __float2bfloat16(b.x); u.h[5] = __float2bfloat16(b.y);
    u.h[6] = __float2bfloat16(b.z); u.h[7] = __float2bfloat16(b.w);
    ((s16x8*)d)[off / 2] = u.p8;
}

// Split-K GEMM: P[z][M,N] = A[M,k0:k1] @ B[N,k0:k1]^T (fp32 partials, no epilogue).
// grid = (N/128, M/128, S). 128x128 tile, BK=64, 4 waves of 4x4 16x16x32 MFMA.
// XOR-swizzled LDS (conflict-free, verified R3/R4): row r stores 16B granule g at slot g^(r&7).
__global__ __launch_bounds__(256, 2)
void gemm_btk(const __hip_bfloat16* __restrict__ A,
              const __hip_bfloat16* __restrict__ Bm,
              float* __restrict__ P,
              const int M, const int N, const int kchunk)
{
    __shared__ __hip_bfloat16 As[128 * 64];
    __shared__ __hip_bfloat16 Bs[128 * 64];

    const int tid  = threadIdx.x;
    const int lane = tid & 63;
    const int wave = tid >> 6;
    const int wm   = wave >> 1, wn = wave & 1;
    const int lm   = lane & 15, lq = lane >> 4;

    const int bn = blockIdx.x, bm = blockIdx.y, kz = blockIdx.z;
    const int K  = kchunk * gridDim.z;
    const int k0 = kz * kchunk;

    const int rlo  = lane >> 3;                  // row within an 8-row staging chunk
    const int gsw8 = (((lane & 7) ^ rlo) << 3);  // swizzled granule -> element offset

    const __hip_bfloat16* Ag = A  + (size_t)(bm * 128) * K;
    const __hip_bfloat16* Bg = Bm + (size_t)(bn * 128) * K;

    f32x4 acc[4][4];
    #pragma unroll
    for (int i = 0; i < 4; ++i)
        #pragma unroll
        for (int j = 0; j < 4; ++j)
            acc[i][j] = (f32x4){0.f, 0.f, 0.f, 0.f};

    for (int kt = k0; kt < k0 + kchunk; kt += 64) {
        __syncthreads();
        #pragma unroll
        for (int c = 0; c < 4; ++c) {
            const int chunk = wave * 4 + c;      // 0..15, wave-uniform
            const int row   = chunk * 8 + rlo;   // local tile row 0..127
            gload_lds16(Ag + (size_t)row * K + kt + gsw8, As + chunk * 512);
            gload_lds16(Bg + (size_t)row * K + kt + gsw8, Bs + chunk * 512);
        }
        __syncthreads();
        #pragma unroll
        for (int kk = 0; kk < 2; ++kk) {
            // granule G = kk*4+lq of row lives at slot G^(row&7); row&7 == lm&7
            const int sl = (((kk * 4 + lq) ^ (lm & 7)) << 3);
            bf16x8 af[4], bf[4];
            #pragma unroll
            for (int i = 0; i < 4; ++i)
                af[i] = *(const bf16x8*)(As + (wm * 64 + i * 16 + lm) * 64 + sl);
            #pragma unroll
            for (int j = 0; j < 4; ++j)
                bf[j] = *(const bf16x8*)(Bs + (wn * 64 + j * 16 + lm) * 64 + sl);
            #pragma unroll
            for (int i = 0; i < 4; ++i)
                #pragma unroll
                for (int j = 0; j < 4; ++j)
                    acc[i][j] = __builtin_amdgcn_mfma_f32_16x16x32_bf16(af[i], bf[j], acc[i][j], 0, 0, 0);
        }
    }

    float* Pz = P + (size_t)kz * M * N;
    const int row0 = bm * 128 + wm * 64;
    const int colb = bn * 128 + wn * 64 + lm;
    #pragma unroll
    for (int j = 0; j < 4; ++j) {
        const int col = colb + j * 16;
        #pragma unroll
        for (int i = 0; i < 4; ++i)
            #pragma unroll
            for (int r = 0; r < 4; ++r) {
                const int row = row0 + i * 16 + lq * 4 + r;
                Pz[(size_t)row * N + col] = acc[i][j][r];
            }
    }
}

// Sum S split-K partials + epilogue (dense, float4, memory-bound). NT loads: partials are dead after this.
// MODE 0: bf16 out = relu(sum + bias)            (layer1 -> D1)
// MODE 1: bf16 out = T-collapse(y=sum, b2)       (layer2 -> Z)
// MODE 2: f32  out = sum + (1-beta3^T)*bias      (layer3 -> s3_T)
template <int MODE>
__global__ void reduce_k(const float* __restrict__ P, const int S,
                         void* __restrict__ outv, const long MN, const int N,
                         const float* __restrict__ bias,
                         const float* __restrict__ b_taus,
                         const int* __restrict__ Tp)
{
    long i4 = (long)blockIdx.x * 256 + threadIdx.x;   // float4 index, exact cover
    long i  = i4 * 4;
    f32x4 a = __builtin_nontemporal_load(((const f32x4*)P) + i4);
    for (int s = 1; s < S; ++s) {
        f32x4 b = __builtin_nontemporal_load((const f32x4*)(P + (size_t)s * MN) + i4);
        a += b;
    }
    const int col = (int)(i % N);
    const float4 bv = *(const float4*)(bias + col);

    if constexpr (MODE == 0) {
        union { s16x4 p; __hip_bfloat16 h[4]; } u;
        u.h[0] = __float2bfloat16(fmaxf(a.x + bv.x, 0.f));
        u.h[1] = __float2bfloat16(fmaxf(a.y + bv.y, 0.f));
        u.h[2] = __float2bfloat16(fmaxf(a.z + bv.z, 0.f));
        u.h[3] = __float2bfloat16(fmaxf(a.w + bv.w, 0.f));
        ((s16x4*)outv)[i4] = u.p;
    } else if constexpr (MODE == 1) {
        const int   T   = *Tp;
        const float be1 = 1.f / (1.f + expf(-b_taus[0]));
        const float be2 = 1.f / (1.f + expf(-b_taus[1]));
        const float be3 = 1.f / (1.f + expf(-b_taus[2]));
        float y[4] = {a.x, a.y, a.z, a.w};
        float bb[4] = {bv.x, bv.y, bv.z, bv.w};
        union { s16x4 p; __hip_bfloat16 h[4]; } u;
        #pragma unroll
        for (int c = 0; c < 4; ++c) {
            float p1 = 1.f, s2 = 0.f, za = 0.f;
            for (int t = 0; t < T; ++t) {
                p1 *= be1;
                const float d2 = fmaxf(fmaf(1.f - p1, y[c], bb[c]), 0.f);
                s2 = be2 * s2 + (1.f - be2) * d2;
                za = be3 * za + (1.f - be3) * s2;
            }
            u.h[c] = __float2bfloat16(za);
        }
        ((s16x4*)outv)[i4] = u.p;
    } else {
        const int   T   = *Tp;
        const float be3 = 1.f / (1.f + expf(-b_taus[2]));
        float g = 0.f;
        for (int t = 0; t < T; ++t) g = be3 * g + (1.f - be3);   // 1 - beta3^T
        float4 o;
        o.x = a.x + g * bv.x;
        o.y = a.y + g * bv.y;
        o.z = a.z + g * bv.z;
        o.w = a.w + g * bv.w;
        ((float4*)outv)[i4] = o;
    }
}

extern "C" void kernel_launch(void* const* d_in, const int* in_sizes, int n_in,
                              void* d_out, int out_size, void* d_ws, size_t ws_size,
                              hipStream_t stream) {
    const float* x      = (const float*)d_in[0];
    const float* W1     = (const float*)d_in[1];
    const float* b1     = (const float*)d_in[2];
    const float* W2     = (const float*)d_in[3];
    const float* b2     = (const float*)d_in[4];
    const float* W3     = (const float*)d_in[5];
    const float* b3     = (const float*)d_in[6];
    const float* b_taus = (const float*)d_in[7];
    const int*   Tp     = (const int*)d_in[8];

    const int B = 1024, DIN = 2048, H1 = 4096, H2 = 4096, DOUT = 1024;
    const long MB = 1024 * 1024;

    // Arena (120 MB), phase-aliased:
    //  phase1: xb 0..4, W1b 4..20, P1 20..52
    //  phase2: P2 0..64          phase3: P3 0..32
    //  static: W2b 64..96, W3b 96..104, D1b 104..112, Sb 112..120
    char* ws = (char*)d_ws;
    __hip_bfloat16* xb  = (__hip_bfloat16*)(ws + 0);
    __hip_bfloat16* W1b = (__hip_bfloat16*)(ws + 4 * MB);
    float*          P1  = (float*)         (ws + 20 * MB);
    float*          P2  = (float*)         (ws + 0);
    float*          P3  = (float*)         (ws + 0);
    __hip_bfloat16* W2b = (__hip_bfloat16*)(ws + 64 * MB);
    __hip_bfloat16* W3b = (__hip_bfloat16*)(ws + 96 * MB);
    __hip_bfloat16* D1b = (__hip_bfloat16*)(ws + 104 * MB);
    __hip_bfloat16* Sb  = (__hip_bfloat16*)(ws + 112 * MB);

    // casts: 3,932,160 float4-pairs exactly
    cast_all_k<<<dim3(15360), dim3(256), 0, stream>>>(x, W1, W2, W3, xb, W1b, W2b, W3b);

    // Layer 1: P1 = split-K(x @ W1^T), S=2   (512 blocks)
    gemm_btk<<<dim3(H1 / 128, B / 128, 2), 256, 0, stream>>>(xb, W1b, P1, B, H1, DIN / 2);
    reduce_k<0><<<dim3(4096), 256, 0, stream>>>(P1, 2, (void*)D1b, (long)B * H1, H1, b1, nullptr, nullptr);

    // Layer 2: P2 = split-K(D1 @ W2^T), S=4  (1024 blocks)
    gemm_btk<<<dim3(H2 / 128, B / 128, 4), 256, 0, stream>>>(D1b, W2b, P2, B, H2, H1 / 4);
    reduce_k<1><<<dim3(4096), 256, 0, stream>>>(P2, 4, (void*)Sb, (long)B * H2, H2, b2, b_taus, Tp);

    // Layer 3: P3 = split-K(Z @ W3^T), S=8   (512 blocks)
    gemm_btk<<<dim3(DOUT / 128, B / 128, 8), 256, 0, stream>>>(Sb, W3b, P3, B, DOUT, H2 / 8);
    reduce_k<2><<<dim3(1024), 256, 0, stream>>>(P3, 8, d_out, (long)B * DOUT, DOUT, b3, b_taus, Tp);
}

// Round 6
// 259.824 us; speedup vs baseline: 2.0420x; 1.0214x over previous
//
#include <hip/hip_runtime.h>
#include <hip/hip_bf16.h>
#include <stdint.h>

#define AS_GLOBAL __attribute__((address_space(1)))
#define AS_LDS    __attribute__((address_space(3)))

typedef __attribute__((ext_vector_type(8))) short  bf16x8;
typedef __attribute__((ext_vector_type(4))) float  f32x4;
typedef __attribute__((ext_vector_type(4))) short  s16x4;
typedef __attribute__((ext_vector_type(8))) short  s16x8;

__device__ __forceinline__ void gload_lds16(const void* g, void* l) {
    __builtin_amdgcn_global_load_lds((AS_GLOBAL const void*)g, (AS_LDS void*)l, 16, 0, 0);
}

// Cast 8 fp32 -> 8 bf16 (one 16B store), pair index p into region (s,d).
__device__ __forceinline__ void cast_pair(const float* __restrict__ s,
                                          __hip_bfloat16* __restrict__ d, long p) {
    f32x4 a = ((const f32x4*)s)[p * 2];
    f32x4 b = ((const f32x4*)s)[p * 2 + 1];
    union { s16x8 p8; __hip_bfloat16 h[8]; } u;
    u.h[0] = __float2bfloat16(a.x); u.h[1] = __float2bfloat16(a.y);
    u.h[2] = __float2bfloat16(a.z); u.h[3] = __float2bfloat16(a.w);
    u.h[4] = __float2bfloat16(b.x); u.h[5] = __float2bfloat16(b.y);
    u.h[6] = __float2bfloat16(b.z); u.h[7] = __float2bfloat16(b.w);
    ((s16x8*)d)[p] = u.p8;
}

// castA: x (262144 pairs) + W1 (1048576 pairs) = 1310720 pairs; 1280 blocks x 256 x 4 iters.
__global__ void cast_a_k(const float* __restrict__ x,  __hip_bfloat16* __restrict__ xb,
                         const float* __restrict__ W1, __hip_bfloat16* __restrict__ W1b) {
    const long nx = 262144, ntot = 1310720, stride = 1280 * 256;
    long t = (long)blockIdx.x * 256 + threadIdx.x;
    for (long p = t; p < ntot; p += stride) {
        if (p < nx) cast_pair(x, xb, p);
        else        cast_pair(W1, W1b, p - nx);
    }
}

// Split-K GEMM: P[z][M,N] = bf16( A[M,k0:k1] @ B[N,k0:k1]^T ).
// grid = (N/128, M/128, S + FUSECAST). 128x128 tile, BK=64, 4 waves, 4x4 16x16x32 MFMA.
// XOR-swizzled LDS (conflict-free, verified R4/R5): row r stores 16B granule g at slot g^(r&7).
// FUSECAST: plane z==S is 256 grid-stride cast blocks (W2,W3 fp32->bf16), overlapped with GEMM.
template <int FUSECAST>
__global__ __launch_bounds__(256, 2)
void gemm_btk(const __hip_bfloat16* __restrict__ A,
              const __hip_bfloat16* __restrict__ Bm,
              __hip_bfloat16* __restrict__ P,
              const int M, const int N, const int kchunk, const int S,
              const float* __restrict__ cs1, __hip_bfloat16* __restrict__ cd1, const long cn1,
              const float* __restrict__ cs2, __hip_bfloat16* __restrict__ cd2, const long cn2)
{
    __shared__ __hip_bfloat16 As[128 * 64];
    __shared__ __hip_bfloat16 Bs[128 * 64];

    const int tid  = threadIdx.x;
    const int bn = blockIdx.x, bm = blockIdx.y, kz = blockIdx.z;

    if (FUSECAST && kz == S) {
        // 256 blocks x 256 threads, grid-stride over cn1+cn2 pairs (all bounds %64==0)
        const long stride = (long)gridDim.x * gridDim.y * 256;
        long t = ((long)bm * gridDim.x + bn) * 256 + tid;
        const long ntot = cn1 + cn2;
        for (long p = t; p < ntot; p += stride) {
            if (p < cn1) cast_pair(cs1, cd1, p);
            else         cast_pair(cs2, cd2, p - cn1);
        }
        return;
    }

    const int lane = tid & 63;
    const int wave = tid >> 6;
    const int wm   = wave >> 1, wn = wave & 1;
    const int lm   = lane & 15, lq = lane >> 4;

    const int K  = kchunk * S;
    const int k0 = kz * kchunk;

    const int rlo  = lane >> 3;                  // row within an 8-row staging chunk
    const int gsw8 = (((lane & 7) ^ rlo) << 3);  // swizzled granule -> element offset

    const __hip_bfloat16* Ag = A  + (size_t)(bm * 128) * K;
    const __hip_bfloat16* Bg = Bm + (size_t)(bn * 128) * K;

    f32x4 acc[4][4];
    #pragma unroll
    for (int i = 0; i < 4; ++i)
        #pragma unroll
        for (int j = 0; j < 4; ++j)
            acc[i][j] = (f32x4){0.f, 0.f, 0.f, 0.f};

    for (int kt = k0; kt < k0 + kchunk; kt += 64) {
        __syncthreads();
        #pragma unroll
        for (int c = 0; c < 4; ++c) {
            const int chunk = wave * 4 + c;      // 0..15, wave-uniform
            const int row   = chunk * 8 + rlo;   // local tile row 0..127
            gload_lds16(Ag + (size_t)row * K + kt + gsw8, As + chunk * 512);
            gload_lds16(Bg + (size_t)row * K + kt + gsw8, Bs + chunk * 512);
        }
        __syncthreads();
        #pragma unroll
        for (int kk = 0; kk < 2; ++kk) {
            // granule G = kk*4+lq of row lives at slot G^(row&7); row&7 == lm&7
            const int sl = (((kk * 4 + lq) ^ (lm & 7)) << 3);
            bf16x8 af[4], bf[4];
            #pragma unroll
            for (int i = 0; i < 4; ++i)
                af[i] = *(const bf16x8*)(As + (wm * 64 + i * 16 + lm) * 64 + sl);
            #pragma unroll
            for (int j = 0; j < 4; ++j)
                bf[j] = *(const bf16x8*)(Bs + (wn * 64 + j * 16 + lm) * 64 + sl);
            #pragma unroll
            for (int i = 0; i < 4; ++i)
                #pragma unroll
                for (int j = 0; j < 4; ++j)
                    acc[i][j] = __builtin_amdgcn_mfma_f32_16x16x32_bf16(af[i], bf[j], acc[i][j], 0, 0, 0);
        }
    }

    __hip_bfloat16* Pz = P + (size_t)kz * M * N;
    const int row0 = bm * 128 + wm * 64;
    const int colb = bn * 128 + wn * 64 + lm;
    #pragma unroll
    for (int j = 0; j < 4; ++j) {
        const int col = colb + j * 16;
        #pragma unroll
        for (int i = 0; i < 4; ++i)
            #pragma unroll
            for (int r = 0; r < 4; ++r) {
                const int row = row0 + i * 16 + lq * 4 + r;
                Pz[(size_t)row * N + col] = __float2bfloat16(acc[i][j][r]);
            }
    }
}

// Sum S bf16 split-K partials (16B loads, fp32 accumulate) + epilogue. 8 elems/thread.
// MODE 0: bf16 out = relu(sum + bias)            (layer1 -> D1)
// MODE 1: bf16 out = T-collapse(y=sum, b2)       (layer2 -> Z)
// MODE 2: f32  out = sum + (1-beta3^T)*bias      (layer3 -> s3_T)
template <int MODE>
__global__ void reduce_k(const __hip_bfloat16* __restrict__ P, const int S,
                         void* __restrict__ outv, const long MN, const int N,
                         const float* __restrict__ bias,
                         const float* __restrict__ b_taus,
                         const int* __restrict__ Tp)
{
    long i8 = (long)blockIdx.x * 256 + threadIdx.x;   // 8-element group, exact cover
    long i  = i8 * 8;
    float a[8] = {0.f, 0.f, 0.f, 0.f, 0.f, 0.f, 0.f, 0.f};
    for (int s = 0; s < S; ++s) {
        union { s16x8 p8; __hip_bfloat16 h[8]; } u;
        u.p8 = *(const s16x8*)(P + (size_t)s * MN + i);
        #pragma unroll
        for (int c = 0; c < 8; ++c) a[c] += __bfloat162float(u.h[c]);
    }
    const int col = (int)(i % N);
    float bb[8];
    #pragma unroll
    for (int c = 0; c < 8; ++c) bb[c] = bias[col + c];

    if constexpr (MODE == 0) {
        union { s16x8 p8; __hip_bfloat16 h[8]; } u;
        #pragma unroll
        for (int c = 0; c < 8; ++c)
            u.h[c] = __float2bfloat16(fmaxf(a[c] + bb[c], 0.f));
        ((s16x8*)outv)[i8] = u.p8;
    } else if constexpr (MODE == 1) {
        const int   T   = *Tp;
        const float be1 = 1.f / (1.f + expf(-b_taus[0]));
        const float be2 = 1.f / (1.f + expf(-b_taus[1]));
        const float be3 = 1.f / (1.f + expf(-b_taus[2]));
        union { s16x8 p8; __hip_bfloat16 h[8]; } u;
        #pragma unroll
        for (int c = 0; c < 8; ++c) {
            float p1 = 1.f, s2 = 0.f, za = 0.f;
            for (int t = 0; t < T; ++t) {
                p1 *= be1;
                const float d2 = fmaxf(fmaf(1.f - p1, a[c], bb[c]), 0.f);
                s2 = be2 * s2 + (1.f - be2) * d2;
                za = be3 * za + (1.f - be3) * s2;
            }
            u.h[c] = __float2bfloat16(za);
        }
        ((s16x8*)outv)[i8] = u.p8;
    } else {
        const int   T   = *Tp;
        const float be3 = 1.f / (1.f + expf(-b_taus[2]));
        float g = 0.f;
        for (int t = 0; t < T; ++t) g = be3 * g + (1.f - be3);   // 1 - beta3^T
        f32x4 o0, o1;
        o0.x = a[0] + g * bb[0]; o0.y = a[1] + g * bb[1];
        o0.z = a[2] + g * bb[2]; o0.w = a[3] + g * bb[3];
        o1.x = a[4] + g * bb[4]; o1.y = a[5] + g * bb[5];
        o1.z = a[6] + g * bb[6]; o1.w = a[7] + g * bb[7];
        ((f32x4*)outv)[i8 * 2]     = o0;
        ((f32x4*)outv)[i8 * 2 + 1] = o1;
    }
}

extern "C" void kernel_launch(void* const* d_in, const int* in_sizes, int n_in,
                              void* d_out, int out_size, void* d_ws, size_t ws_size,
                              hipStream_t stream) {
    const float* x      = (const float*)d_in[0];
    const float* W1     = (const float*)d_in[1];
    const float* b1     = (const float*)d_in[2];
    const float* W2     = (const float*)d_in[3];
    const float* b2     = (const float*)d_in[4];
    const float* W3     = (const float*)d_in[5];
    const float* b3     = (const float*)d_in[6];
    const float* b_taus = (const float*)d_in[7];
    const int*   Tp     = (const int*)d_in[8];

    const int B = 1024, DIN = 2048, H1 = 4096, H2 = 4096, DOUT = 1024;
    const long MB = 1024 * 1024;

    // Arena (140 MB, no aliasing): xb 0, W1b 4, W2b 20, W3b 52, D1b 60, Sb 68,
    // P1 76 (16MB), P2 92 (32MB), P3 124 (16MB)   [bf16 partials]
    char* ws = (char*)d_ws;
    __hip_bfloat16* xb  = (__hip_bfloat16*)(ws + 0);
    __hip_bfloat16* W1b = (__hip_bfloat16*)(ws + 4 * MB);
    __hip_bfloat16* W2b = (__hip_bfloat16*)(ws + 20 * MB);
    __hip_bfloat16* W3b = (__hip_bfloat16*)(ws + 52 * MB);
    __hip_bfloat16* D1b = (__hip_bfloat16*)(ws + 60 * MB);
    __hip_bfloat16* Sb  = (__hip_bfloat16*)(ws + 68 * MB);
    __hip_bfloat16* P1  = (__hip_bfloat16*)(ws + 76 * MB);
    __hip_bfloat16* P2  = (__hip_bfloat16*)(ws + 92 * MB);
    __hip_bfloat16* P3  = (__hip_bfloat16*)(ws + 124 * MB);

    // castA: x + W1 only (gates gemm1)
    cast_a_k<<<dim3(1280), dim3(256), 0, stream>>>(x, xb, W1, W1b);

    // Layer 1 GEMM (S=2, 512 blocks) + fused W2/W3 cast plane (256 blocks, overlapped)
    gemm_btk<1><<<dim3(H1 / 128, B / 128, 3), 256, 0, stream>>>(
        xb, W1b, P1, B, H1, DIN / 2, 2,
        W2, W2b, (long)H2 * H1 / 8, W3, W3b, (long)DOUT * H2 / 8);
    reduce_k<0><<<dim3(2048), 256, 0, stream>>>(P1, 2, (void*)D1b, (long)B * H1, H1, b1, nullptr, nullptr);

    // Layer 2: S=4, 1024 blocks
    gemm_btk<0><<<dim3(H2 / 128, B / 128, 4), 256, 0, stream>>>(
        D1b, W2b, P2, B, H2, H1 / 4, 4, nullptr, nullptr, 0, nullptr, nullptr, 0);
    reduce_k<1><<<dim3(2048), 256, 0, stream>>>(P2, 4, (void*)Sb, (long)B * H2, H2, b2, b_taus, Tp);

    // Layer 3: S=8, 512 blocks
    gemm_btk<0><<<dim3(DOUT / 128, B / 128, 8), 256, 0, stream>>>(
        Sb, W3b, P3, B, DOUT, H2 / 8, 8, nullptr, nullptr, 0, nullptr, nullptr, 0);
    reduce_k<2><<<dim3(512), 256, 0, stream>>>(P3, 8, d_out, (long)B * DOUT, DOUT, b3, b_taus, Tp);
}

// Round 7
// 257.021 us; speedup vs baseline: 2.0643x; 1.0109x over previous
//
#include <hip/hip_runtime.h>
#include <hip/hip_bf16.h>
#include <stdint.h>

#define AS_GLOBAL __attribute__((address_space(1)))
#define AS_LDS    __attribute__((address_space(3)))

typedef __attribute__((ext_vector_type(8))) short  bf16x8;
typedef __attribute__((ext_vector_type(4))) float  f32x4;
typedef __attribute__((ext_vector_type(4))) short  s16x4;
typedef __attribute__((ext_vector_type(8))) short  s16x8;

__device__ __forceinline__ void gload_lds16(const void* g, void* l) {
    __builtin_amdgcn_global_load_lds((AS_GLOBAL const void*)g, (AS_LDS void*)l, 16, 0, 0);
}

// Cast 8 fp32 -> 8 bf16 (one 16B store), pair index p into region (s,d).
__device__ __forceinline__ void cast_pair(const float* __restrict__ s,
                                          __hip_bfloat16* __restrict__ d, long p) {
    f32x4 a = ((const f32x4*)s)[p * 2];
    f32x4 b = ((const f32x4*)s)[p * 2 + 1];
    union { s16x8 p8; __hip_bfloat16 h[8]; } u;
    u.h[0] = __float2bfloat16(a.x); u.h[1] = __float2bfloat16(a.y);
    u.h[2] = __float2bfloat16(a.z); u.h[3] = __float2bfloat16(a.w);
    u.h[4] = __float2bfloat16(b.x); u.h[5] = __float2bfloat16(b.y);
    u.h[6] = __float2bfloat16(b.z); u.h[7] = __float2bfloat16(b.w);
    ((s16x8*)d)[p] = u.p8;
}

// castA: x (262144 pairs) + W1 (1048576 pairs) = 1310720 pairs; 1280 blocks x 256 x 4 iters.
__global__ void cast_a_k(const float* __restrict__ x,  __hip_bfloat16* __restrict__ xb,
                         const float* __restrict__ W1, __hip_bfloat16* __restrict__ W1b) {
    const long nx = 262144, ntot = 1310720, stride = 1280 * 256;
    long t = (long)blockIdx.x * 256 + threadIdx.x;
    for (long p = t; p < ntot; p += stride) {
        if (p < nx) cast_pair(x, xb, p);
        else        cast_pair(W1, W1b, p - nx);
    }
}

// Split-K GEMM: P[z][M,N] = bf16( A[M,k0:k1] @ B[N,k0:k1]^T ).
// grid = (N/128, M/128, CP + S) where CP = FUSECAST cast planes come FIRST
// (z = 0..CP-1) so they hit the CUs before the GEMM wave and stream W2/W3
// fp32->bf16 concurrently with GEMM compute (VMEM pipe vs MFMA pipe overlap).
// GEMM planes: z' = z - CP. 128x128 tile, BK=64, 4 waves, 4x4 16x16x32 MFMA.
// XOR-swizzled LDS (conflict-free, verified R4-R6): row r stores 16B granule g at slot g^(r&7).
template <int FUSECAST>
__global__ __launch_bounds__(256, 2)
void gemm_btk(const __hip_bfloat16* __restrict__ A,
              const __hip_bfloat16* __restrict__ Bm,
              __hip_bfloat16* __restrict__ P,
              const int M, const int N, const int kchunk, const int S,
              const float* __restrict__ cs1, __hip_bfloat16* __restrict__ cd1, const long cn1,
              const float* __restrict__ cs2, __hip_bfloat16* __restrict__ cd2, const long cn2)
{
    __shared__ __hip_bfloat16 As[128 * 64];
    __shared__ __hip_bfloat16 Bs[128 * 64];

    const int tid = threadIdx.x;
    const int bn = blockIdx.x, bm = blockIdx.y, z = blockIdx.z;

    if (FUSECAST && z < FUSECAST) {
        // CP*gridDim.x*gridDim.y blocks, grid-stride over cn1+cn2 pairs
        const long nb     = (long)gridDim.x * gridDim.y;
        const long stride = FUSECAST * nb * 256;
        long t = ((long)z * nb + (long)bm * gridDim.x + bn) * 256 + tid;
        const long ntot = cn1 + cn2;
        for (long p = t; p < ntot; p += stride) {
            if (p < cn1) cast_pair(cs1, cd1, p);
            else         cast_pair(cs2, cd2, p - cn1);
        }
        return;
    }
    const int kz = z - FUSECAST;

    const int lane = tid & 63;
    const int wave = tid >> 6;
    const int wm   = wave >> 1, wn = wave & 1;
    const int lm   = lane & 15, lq = lane >> 4;

    const int K  = kchunk * S;
    const int k0 = kz * kchunk;

    const int rlo  = lane >> 3;                  // row within an 8-row staging chunk
    const int gsw8 = (((lane & 7) ^ rlo) << 3);  // swizzled granule -> element offset

    const __hip_bfloat16* Ag = A  + (size_t)(bm * 128) * K;
    const __hip_bfloat16* Bg = Bm + (size_t)(bn * 128) * K;

    f32x4 acc[4][4];
    #pragma unroll
    for (int i = 0; i < 4; ++i)
        #pragma unroll
        for (int j = 0; j < 4; ++j)
            acc[i][j] = (f32x4){0.f, 0.f, 0.f, 0.f};

    for (int kt = k0; kt < k0 + kchunk; kt += 64) {
        __syncthreads();
        #pragma unroll
        for (int c = 0; c < 4; ++c) {
            const int chunk = wave * 4 + c;      // 0..15, wave-uniform
            const int row   = chunk * 8 + rlo;   // local tile row 0..127
            gload_lds16(Ag + (size_t)row * K + kt + gsw8, As + chunk * 512);
            gload_lds16(Bg + (size_t)row * K + kt + gsw8, Bs + chunk * 512);
        }
        __syncthreads();
        #pragma unroll
        for (int kk = 0; kk < 2; ++kk) {
            // granule G = kk*4+lq of row lives at slot G^(row&7); row&7 == lm&7
            const int sl = (((kk * 4 + lq) ^ (lm & 7)) << 3);
            bf16x8 af[4], bf[4];
            #pragma unroll
            for (int i = 0; i < 4; ++i)
                af[i] = *(const bf16x8*)(As + (wm * 64 + i * 16 + lm) * 64 + sl);
            #pragma unroll
            for (int j = 0; j < 4; ++j)
                bf[j] = *(const bf16x8*)(Bs + (wn * 64 + j * 16 + lm) * 64 + sl);
            #pragma unroll
            for (int i = 0; i < 4; ++i)
                #pragma unroll
                for (int j = 0; j < 4; ++j)
                    acc[i][j] = __builtin_amdgcn_mfma_f32_16x16x32_bf16(af[i], bf[j], acc[i][j], 0, 0, 0);
        }
    }

    __hip_bfloat16* Pz = P + (size_t)kz * M * N;
    const int row0 = bm * 128 + wm * 64;
    const int colb = bn * 128 + wn * 64 + lm;
    #pragma unroll
    for (int j = 0; j < 4; ++j) {
        const int col = colb + j * 16;
        #pragma unroll
        for (int i = 0; i < 4; ++i)
            #pragma unroll
            for (int r = 0; r < 4; ++r) {
                const int row = row0 + i * 16 + lq * 4 + r;
                Pz[(size_t)row * N + col] = __float2bfloat16(acc[i][j][r]);
            }
    }
}

// Sum S bf16 split-K partials (16B loads, fp32 accumulate) + epilogue. 8 elems/thread.
// MODE 0: bf16 out = relu(sum + bias)            (layer1 -> D1)
// MODE 1: bf16 out = T-collapse(y=sum, b2)       (layer2 -> Z)
// MODE 2: f32  out = sum + (1-beta3^T)*bias      (layer3 -> s3_T)
template <int MODE>
__global__ void reduce_k(const __hip_bfloat16* __restrict__ P, const int S,
                         void* __restrict__ outv, const long MN, const int N,
                         const float* __restrict__ bias,
                         const float* __restrict__ b_taus,
                         const int* __restrict__ Tp)
{
    long i8 = (long)blockIdx.x * 256 + threadIdx.x;   // 8-element group, exact cover
    long i  = i8 * 8;
    float a[8] = {0.f, 0.f, 0.f, 0.f, 0.f, 0.f, 0.f, 0.f};
    for (int s = 0; s < S; ++s) {
        union { s16x8 p8; __hip_bfloat16 h[8]; } u;
        u.p8 = *(const s16x8*)(P + (size_t)s * MN + i);
        #pragma unroll
        for (int c = 0; c < 8; ++c) a[c] += __bfloat162float(u.h[c]);
    }
    const int col = (int)(i % N);
    float bb[8];
    #pragma unroll
    for (int c = 0; c < 8; ++c) bb[c] = bias[col + c];

    if constexpr (MODE == 0) {
        union { s16x8 p8; __hip_bfloat16 h[8]; } u;
        #pragma unroll
        for (int c = 0; c < 8; ++c)
            u.h[c] = __float2bfloat16(fmaxf(a[c] + bb[c], 0.f));
        ((s16x8*)outv)[i8] = u.p8;
    } else if constexpr (MODE == 1) {
        const int   T   = *Tp;
        const float be1 = 1.f / (1.f + expf(-b_taus[0]));
        const float be2 = 1.f / (1.f + expf(-b_taus[1]));
        const float be3 = 1.f / (1.f + expf(-b_taus[2]));
        union { s16x8 p8; __hip_bfloat16 h[8]; } u;
        #pragma unroll
        for (int c = 0; c < 8; ++c) {
            float p1 = 1.f, s2 = 0.f, za = 0.f;
            for (int t = 0; t < T; ++t) {
                p1 *= be1;
                const float d2 = fmaxf(fmaf(1.f - p1, a[c], bb[c]), 0.f);
                s2 = be2 * s2 + (1.f - be2) * d2;
                za = be3 * za + (1.f - be3) * s2;
            }
            u.h[c] = __float2bfloat16(za);
        }
        ((s16x8*)outv)[i8] = u.p8;
    } else {
        const int   T   = *Tp;
        const float be3 = 1.f / (1.f + expf(-b_taus[2]));
        float g = 0.f;
        for (int t = 0; t < T; ++t) g = be3 * g + (1.f - be3);   // 1 - beta3^T
        f32x4 o0, o1;
        o0.x = a[0] + g * bb[0]; o0.y = a[1] + g * bb[1];
        o0.z = a[2] + g * bb[2]; o0.w = a[3] + g * bb[3];
        o1.x = a[4] + g * bb[4]; o1.y = a[5] + g * bb[5];
        o1.z = a[6] + g * bb[6]; o1.w = a[7] + g * bb[7];
        ((f32x4*)outv)[i8 * 2]     = o0;
        ((f32x4*)outv)[i8 * 2 + 1] = o1;
    }
}

extern "C" void kernel_launch(void* const* d_in, const int* in_sizes, int n_in,
                              void* d_out, int out_size, void* d_ws, size_t ws_size,
                              hipStream_t stream) {
    const float* x      = (const float*)d_in[0];
    const float* W1     = (const float*)d_in[1];
    const float* b1     = (const float*)d_in[2];
    const float* W2     = (const float*)d_in[3];
    const float* b2     = (const float*)d_in[4];
    const float* W3     = (const float*)d_in[5];
    const float* b3     = (const float*)d_in[6];
    const float* b_taus = (const float*)d_in[7];
    const int*   Tp     = (const int*)d_in[8];

    const int B = 1024, DIN = 2048, H1 = 4096, H2 = 4096, DOUT = 1024;
    const long MB = 1024 * 1024;

    // Arena (140 MB, no aliasing): xb 0, W1b 4, W2b 20, W3b 52, D1b 60, Sb 68,
    // P1 76 (16MB), P2 92 (32MB), P3 124 (16MB)   [bf16 partials]
    char* ws = (char*)d_ws;
    __hip_bfloat16* xb  = (__hip_bfloat16*)(ws + 0);
    __hip_bfloat16* W1b = (__hip_bfloat16*)(ws + 4 * MB);
    __hip_bfloat16* W2b = (__hip_bfloat16*)(ws + 20 * MB);
    __hip_bfloat16* W3b = (__hip_bfloat16*)(ws + 52 * MB);
    __hip_bfloat16* D1b = (__hip_bfloat16*)(ws + 60 * MB);
    __hip_bfloat16* Sb  = (__hip_bfloat16*)(ws + 68 * MB);
    __hip_bfloat16* P1  = (__hip_bfloat16*)(ws + 76 * MB);
    __hip_bfloat16* P2  = (__hip_bfloat16*)(ws + 92 * MB);
    __hip_bfloat16* P3  = (__hip_bfloat16*)(ws + 124 * MB);

    // castA: x + W1 only (gates gemm1)
    cast_a_k<<<dim3(1280), dim3(256), 0, stream>>>(x, xb, W1, W1b);

    // Layer 1 GEMM (S=2) + 2 leading cast planes (W2/W3, 512 blocks, dispatched FIRST)
    gemm_btk<2><<<dim3(H1 / 128, B / 128, 2 + 2), 256, 0, stream>>>(
        xb, W1b, P1, B, H1, DIN / 2, 2,
        W2, W2b, (long)H2 * H1 / 8, W3, W3b, (long)DOUT * H2 / 8);
    reduce_k<0><<<dim3(2048), 256, 0, stream>>>(P1, 2, (void*)D1b, (long)B * H1, H1, b1, nullptr, nullptr);

    // Layer 2: S=4, 1024 blocks
    gemm_btk<0><<<dim3(H2 / 128, B / 128, 4), 256, 0, stream>>>(
        D1b, W2b, P2, B, H2, H1 / 4, 4, nullptr, nullptr, 0, nullptr, nullptr, 0);
    reduce_k<1><<<dim3(2048), 256, 0, stream>>>(P2, 4, (void*)Sb, (long)B * H2, H2, b2, b_taus, Tp);

    // Layer 3: S=8, 512 blocks
    gemm_btk<0><<<dim3(DOUT / 128, B / 128, 8), 256, 0, stream>>>(
        Sb, W3b, P3, B, DOUT, H2 / 8, 8, nullptr, nullptr, 0, nullptr, nullptr, 0);
    reduce_k<2><<<dim3(512), 256, 0, stream>>>(P3, 8, d_out, (long)B * DOUT, DOUT, b3, b_taus, Tp);
}

// Round 8
// 250.620 us; speedup vs baseline: 2.1170x; 1.0255x over previous
//
#include <hip/hip_runtime.h>
#include <hip/hip_bf16.h>
#include <stdint.h>

#define AS_GLOBAL __attribute__((address_space(1)))
#define AS_LDS    __attribute__((address_space(3)))

typedef __attribute__((ext_vector_type(8))) short  bf16x8;
typedef __attribute__((ext_vector_type(4))) float  f32x4;
typedef __attribute__((ext_vector_type(4))) short  s16x4;
typedef __attribute__((ext_vector_type(8))) short  s16x8;

__device__ __forceinline__ void gload_lds16(const void* g, void* l) {
    __builtin_amdgcn_global_load_lds((AS_GLOBAL const void*)g, (AS_LDS void*)l, 16, 0, 0);
}

// Cast 8 fp32 -> 8 bf16 (one 16B store), pair index p into region (s,d).
__device__ __forceinline__ void cast_pair(const float* __restrict__ s,
                                          __hip_bfloat16* __restrict__ d, long p) {
    f32x4 a = ((const f32x4*)s)[p * 2];
    f32x4 b = ((const f32x4*)s)[p * 2 + 1];
    union { s16x8 p8; __hip_bfloat16 h[8]; } u;
    u.h[0] = __float2bfloat16(a.x); u.h[1] = __float2bfloat16(a.y);
    u.h[2] = __float2bfloat16(a.z); u.h[3] = __float2bfloat16(a.w);
    u.h[4] = __float2bfloat16(b.x); u.h[5] = __float2bfloat16(b.y);
    u.h[6] = __float2bfloat16(b.z); u.h[7] = __float2bfloat16(b.w);
    ((s16x8*)d)[p] = u.p8;
}

// castA: x (262144 pairs) + W1 (1048576 pairs) = 1310720 pairs; 1280 blocks x 256 x 4 iters.
__global__ void cast_a_k(const float* __restrict__ x,  __hip_bfloat16* __restrict__ xb,
                         const float* __restrict__ W1, __hip_bfloat16* __restrict__ W1b) {
    const long nx = 262144, ntot = 1310720, stride = 1280 * 256;
    long t = (long)blockIdx.x * 256 + threadIdx.x;
    for (long p = t; p < ntot; p += stride) {
        if (p < nx) cast_pair(x, xb, p);
        else        cast_pair(W1, W1b, p - nx);
    }
}

// Split-K GEMM: P[z][M,N] = bf16( A[M,k0:k1] @ B[N,k0:k1]^T ).
// grid = (N/128, M/128, CP + S) where CP = FUSECAST leading cast planes
// (z < CP). CP=1 -> 256 cast blocks = exactly 1 slot/CU, so GEMM blocks are
// co-resident from t=0 and the fp32->bf16 stream (VMEM pipe) overlaps GEMM
// (MFMA pipe) per m114. launch_bounds(256,3): 3 blocks/CU (LDS 96KB<160).
// GEMM planes: z' = z - CP. 128x128 tile, BK=64, 4 waves, 4x4 16x16x32 MFMA.
// XOR-swizzled LDS (conflict-free, verified R4-R7): row r stores 16B granule g at slot g^(r&7).
template <int FUSECAST>
__global__ __launch_bounds__(256, 3)
void gemm_btk(const __hip_bfloat16* __restrict__ A,
              const __hip_bfloat16* __restrict__ Bm,
              __hip_bfloat16* __restrict__ P,
              const int M, const int N, const int kchunk, const int S,
              const float* __restrict__ cs1, __hip_bfloat16* __restrict__ cd1, const long cn1,
              const float* __restrict__ cs2, __hip_bfloat16* __restrict__ cd2, const long cn2)
{
    __shared__ __hip_bfloat16 As[128 * 64];
    __shared__ __hip_bfloat16 Bs[128 * 64];

    const int tid = threadIdx.x;
    const int bn = blockIdx.x, bm = blockIdx.y, z = blockIdx.z;

    if (FUSECAST && z < FUSECAST) {
        const long nb     = (long)gridDim.x * gridDim.y;
        const long stride = FUSECAST * nb * 256;
        long t = ((long)z * nb + (long)bm * gridDim.x + bn) * 256 + tid;
        const long ntot = cn1 + cn2;
        for (long p = t; p < ntot; p += stride) {
            if (p < cn1) cast_pair(cs1, cd1, p);
            else         cast_pair(cs2, cd2, p - cn1);
        }
        return;
    }
    const int kz = z - FUSECAST;

    const int lane = tid & 63;
    const int wave = tid >> 6;
    const int wm   = wave >> 1, wn = wave & 1;
    const int lm   = lane & 15, lq = lane >> 4;

    const int K  = kchunk * S;
    const int k0 = kz * kchunk;

    const int rlo  = lane >> 3;                  // row within an 8-row staging chunk
    const int gsw8 = (((lane & 7) ^ rlo) << 3);  // swizzled granule -> element offset

    const __hip_bfloat16* Ag = A  + (size_t)(bm * 128) * K;
    const __hip_bfloat16* Bg = Bm + (size_t)(bn * 128) * K;

    f32x4 acc[4][4];
    #pragma unroll
    for (int i = 0; i < 4; ++i)
        #pragma unroll
        for (int j = 0; j < 4; ++j)
            acc[i][j] = (f32x4){0.f, 0.f, 0.f, 0.f};

    for (int kt = k0; kt < k0 + kchunk; kt += 64) {
        __syncthreads();
        #pragma unroll
        for (int c = 0; c < 4; ++c) {
            const int chunk = wave * 4 + c;      // 0..15, wave-uniform
            const int row   = chunk * 8 + rlo;   // local tile row 0..127
            gload_lds16(Ag + (size_t)row * K + kt + gsw8, As + chunk * 512);
            gload_lds16(Bg + (size_t)row * K + kt + gsw8, Bs + chunk * 512);
        }
        __syncthreads();
        #pragma unroll
        for (int kk = 0; kk < 2; ++kk) {
            // granule G = kk*4+lq of row lives at slot G^(row&7); row&7 == lm&7
            const int sl = (((kk * 4 + lq) ^ (lm & 7)) << 3);
            bf16x8 af[4], bf[4];
            #pragma unroll
            for (int i = 0; i < 4; ++i)
                af[i] = *(const bf16x8*)(As + (wm * 64 + i * 16 + lm) * 64 + sl);
            #pragma unroll
            for (int j = 0; j < 4; ++j)
                bf[j] = *(const bf16x8*)(Bs + (wn * 64 + j * 16 + lm) * 64 + sl);
            #pragma unroll
            for (int i = 0; i < 4; ++i)
                #pragma unroll
                for (int j = 0; j < 4; ++j)
                    acc[i][j] = __builtin_amdgcn_mfma_f32_16x16x32_bf16(af[i], bf[j], acc[i][j], 0, 0, 0);
        }
    }

    __hip_bfloat16* Pz = P + (size_t)kz * M * N;
    const int row0 = bm * 128 + wm * 64;
    const int colb = bn * 128 + wn * 64 + lm;
    #pragma unroll
    for (int j = 0; j < 4; ++j) {
        const int col = colb + j * 16;
        #pragma unroll
        for (int i = 0; i < 4; ++i)
            #pragma unroll
            for (int r = 0; r < 4; ++r) {
                const int row = row0 + i * 16 + lq * 4 + r;
                Pz[(size_t)row * N + col] = __float2bfloat16(acc[i][j][r]);
            }
    }
}

// T-collapse: za = sum_{u=1..T} w_u * relu(c_u*y + b2), where
// c_u = 1-beta1^u, w_u = (1-b2f)(1-b3f)*g_u, g_u = b2f*g_{u+1} + b3f^(T-u), g_T=1.
// Exact algebra of the s2/za double recurrence; independent terms -> ILP.
template <int TT>
__device__ __forceinline__ void tcollapse_coef(float be1, float be2, float be3,
                                               float* __restrict__ c, float* __restrict__ w) {
    float g[TT + 1];
    g[TT] = 1.f;
    float p3 = 1.f;                      // beta3^(T-u), u descending
    #pragma unroll
    for (int u = TT - 1; u >= 1; --u) {
        p3 *= be3;
        g[u] = be2 * g[u + 1] + p3;
    }
    const float s = (1.f - be2) * (1.f - be3);
    float p1 = 1.f;
    #pragma unroll
    for (int u = 1; u <= TT; ++u) {
        p1 *= be1;
        c[u - 1] = 1.f - p1;
        w[u - 1] = s * g[u];
    }
}

// Sum S bf16 split-K partials (16B loads, fp32 accumulate) + epilogue. 8 elems/thread.
// MODE 0: bf16 out = relu(sum + bias)            (layer1 -> D1)
// MODE 1: bf16 out = T-collapse(y=sum, b2)       (layer2 -> Z)
// MODE 2: f32  out = sum + (1-beta3^T)*bias      (layer3 -> s3_T)
template <int MODE>
__global__ void reduce_k(const __hip_bfloat16* __restrict__ P, const int S,
                         void* __restrict__ outv, const long MN, const int N,
                         const float* __restrict__ bias,
                         const float* __restrict__ b_taus,
                         const int* __restrict__ Tp)
{
    long i8 = (long)blockIdx.x * 256 + threadIdx.x;   // 8-element group, exact cover
    long i  = i8 * 8;
    float a[8] = {0.f, 0.f, 0.f, 0.f, 0.f, 0.f, 0.f, 0.f};
    for (int s = 0; s < S; ++s) {
        union { s16x8 p8; __hip_bfloat16 h[8]; } u;
        u.p8 = *(const s16x8*)(P + (size_t)s * MN + i);
        #pragma unroll
        for (int c = 0; c < 8; ++c) a[c] += __bfloat162float(u.h[c]);
    }
    const int col = (int)(i % N);
    float bb[8];
    #pragma unroll
    for (int c = 0; c < 8; ++c) bb[c] = bias[col + c];

    if constexpr (MODE == 0) {
        union { s16x8 p8; __hip_bfloat16 h[8]; } u;
        #pragma unroll
        for (int c = 0; c < 8; ++c)
            u.h[c] = __float2bfloat16(fmaxf(a[c] + bb[c], 0.f));
        ((s16x8*)outv)[i8] = u.p8;
    } else if constexpr (MODE == 1) {
        const int   T   = *Tp;
        const float be1 = 1.f / (1.f + expf(-b_taus[0]));
        const float be2 = 1.f / (1.f + expf(-b_taus[1]));
        const float be3 = 1.f / (1.f + expf(-b_taus[2]));
        union { s16x8 p8; __hip_bfloat16 h[8]; } u;
        if (T == 10) {                     // fast path: fully unrolled, 10 independent terms
            float c10[10], w10[10];
            tcollapse_coef<10>(be1, be2, be3, c10, w10);
            #pragma unroll
            for (int c = 0; c < 8; ++c) {
                float za = 0.f;
                #pragma unroll
                for (int t = 0; t < 10; ++t)
                    za += w10[t] * fmaxf(fmaf(c10[t], a[c], bb[c]), 0.f);
                u.h[c] = __float2bfloat16(za);
            }
        } else {                           // generic fallback (original recurrence)
            #pragma unroll
            for (int c = 0; c < 8; ++c) {
                float p1 = 1.f, s2 = 0.f, za = 0.f;
                for (int t = 0; t < T; ++t) {
                    p1 *= be1;
                    const float d2 = fmaxf(fmaf(1.f - p1, a[c], bb[c]), 0.f);
                    s2 = be2 * s2 + (1.f - be2) * d2;
                    za = be3 * za + (1.f - be3) * s2;
                }
                u.h[c] = __float2bfloat16(za);
            }
        }
        ((s16x8*)outv)[i8] = u.p8;
    } else {
        const int   T   = *Tp;
        const float be3 = 1.f / (1.f + expf(-b_taus[2]));
        float g = 0.f;
        for (int t = 0; t < T; ++t) g = be3 * g + (1.f - be3);   // 1 - beta3^T
        f32x4 o0, o1;
        o0.x = a[0] + g * bb[0]; o0.y = a[1] + g * bb[1];
        o0.z = a[2] + g * bb[2]; o0.w = a[3] + g * bb[3];
        o1.x = a[4] + g * bb[4]; o1.y = a[5] + g * bb[5];
        o1.z = a[6] + g * bb[6]; o1.w = a[7] + g * bb[7];
        ((f32x4*)outv)[i8 * 2]     = o0;
        ((f32x4*)outv)[i8 * 2 + 1] = o1;
    }
}

extern "C" void kernel_launch(void* const* d_in, const int* in_sizes, int n_in,
                              void* d_out, int out_size, void* d_ws, size_t ws_size,
                              hipStream_t stream) {
    const float* x      = (const float*)d_in[0];
    const float* W1     = (const float*)d_in[1];
    const float* b1     = (const float*)d_in[2];
    const float* W2     = (const float*)d_in[3];
    const float* b2     = (const float*)d_in[4];
    const float* W3     = (const float*)d_in[5];
    const float* b3     = (const float*)d_in[6];
    const float* b_taus = (const float*)d_in[7];
    const int*   Tp     = (const int*)d_in[8];

    const int B = 1024, DIN = 2048, H1 = 4096, H2 = 4096, DOUT = 1024;
    const long MB = 1024 * 1024;

    // Arena (140 MB, no aliasing): xb 0, W1b 4, W2b 20, W3b 52, D1b 60, Sb 68,
    // P1 76 (16MB), P2 92 (32MB), P3 124 (16MB)   [bf16 partials]
    char* ws = (char*)d_ws;
    __hip_bfloat16* xb  = (__hip_bfloat16*)(ws + 0);
    __hip_bfloat16* W1b = (__hip_bfloat16*)(ws + 4 * MB);
    __hip_bfloat16* W2b = (__hip_bfloat16*)(ws + 20 * MB);
    __hip_bfloat16* W3b = (__hip_bfloat16*)(ws + 52 * MB);
    __hip_bfloat16* D1b = (__hip_bfloat16*)(ws + 60 * MB);
    __hip_bfloat16* Sb  = (__hip_bfloat16*)(ws + 68 * MB);
    __hip_bfloat16* P1  = (__hip_bfloat16*)(ws + 76 * MB);
    __hip_bfloat16* P2  = (__hip_bfloat16*)(ws + 92 * MB);
    __hip_bfloat16* P3  = (__hip_bfloat16*)(ws + 124 * MB);

    // castA: x + W1 only (gates gemm1)
    cast_a_k<<<dim3(1280), dim3(256), 0, stream>>>(x, xb, W1, W1b);

    // Layer 1 GEMM (S=2) + 1 leading cast plane (W2/W3, 256 blocks = 1 slot/CU)
    gemm_btk<1><<<dim3(H1 / 128, B / 128, 1 + 2), 256, 0, stream>>>(
        xb, W1b, P1, B, H1, DIN / 2, 2,
        W2, W2b, (long)H2 * H1 / 8, W3, W3b, (long)DOUT * H2 / 8);
    reduce_k<0><<<dim3(2048), 256, 0, stream>>>(P1, 2, (void*)D1b, (long)B * H1, H1, b1, nullptr, nullptr);

    // Layer 2: S=4, 1024 blocks
    gemm_btk<0><<<dim3(H2 / 128, B / 128, 4), 256, 0, stream>>>(
        D1b, W2b, P2, B, H2, H1 / 4, 4, nullptr, nullptr, 0, nullptr, nullptr, 0);
    reduce_k<1><<<dim3(2048), 256, 0, stream>>>(P2, 4, (void*)Sb, (long)B * H2, H2, b2, b_taus, Tp);

    // Layer 3: S=8, 512 blocks
    gemm_btk<0><<<dim3(DOUT / 128, B / 128, 8), 256, 0, stream>>>(
        Sb, W3b, P3, B, DOUT, H2 / 8, 8, nullptr, nullptr, 0, nullptr, nullptr, 0);
    reduce_k<2><<<dim3(512), 256, 0, stream>>>(P3, 8, d_out, (long)B * DOUT, DOUT, b3, b_taus, Tp);
}